// Round 11
// baseline (119.352 us; speedup 1.0000x reference)
//
#include <hip/hip_runtime.h>
#include <cstdint>
#include <cstddef>

// ---------------- types ----------------
typedef __bf16 bf16x8 __attribute__((ext_vector_type(8)));
typedef __bf16 bf16x4 __attribute__((ext_vector_type(4)));
typedef float  f32x4  __attribute__((ext_vector_type(4)));
typedef short  s16x4  __attribute__((ext_vector_type(4)));

#define DIMD 1024
#define SEQ  2048
#define NB   2
#define NH   16
#define HD   64
#define QKVN 1536   // 1024 + 2*256
#define VOFF 1280   // DIMD + 256
#define VSTR 2080   // padded V^T row stride (4160B: breaks L2 channel aliasing)
#define CSC  0.18033688011112042f   // 0.125 * log2(e), folded into q in GEMM1

#if __has_builtin(__builtin_amdgcn_mfma_f32_16x16x16bf16_1k)
#define HAS_MFMA16 1
#else
#define HAS_MFMA16 0
#endif

// async global->LDS (16B per lane, wave-uniform LDS base)
typedef __attribute__((address_space(1))) const void* as1_cvp;
typedef __attribute__((address_space(3))) void* as3_vp;
#define GLL16(g, l) __builtin_amdgcn_global_load_lds((as1_cvp)(const void*)(g), (as3_vp)(void*)(l), 16, 0, 0)

// ---------------- fp32 -> bf16 elementwise (vec4) ----------------
__global__ void cvt_f32_bf16(const float* __restrict__ in, __bf16* __restrict__ out, int n4) {
    int i = blockIdx.x * blockDim.x + threadIdx.x;
    if (i >= n4) return;
    float4 v = reinterpret_cast<const float4*>(in)[i];
    bf16x4 o;
    o[0] = (__bf16)v.x; o[1] = (__bf16)v.y; o[2] = (__bf16)v.z; o[3] = (__bf16)v.w;
    reinterpret_cast<bf16x4*>(out)[i] = o;
}

// ---------------- fp32 [R][C] -> bf16 [C][R] tiled transpose ----------------
__global__ void transpose_cvt(const float* __restrict__ in, __bf16* __restrict__ out, int R, int C) {
    __shared__ float t[32][33];
    int bx = blockIdx.x * 32;
    int by = blockIdx.y * 32;
    int tx = threadIdx.x, ty = threadIdx.y;   // (32, 8)
#pragma unroll
    for (int i = 0; i < 32; i += 8)
        t[ty + i][tx] = in[(size_t)(by + ty + i) * C + bx + tx];
    __syncthreads();
#pragma unroll
    for (int i = 0; i < 32; i += 8)
        out[(size_t)(bx + ty + i) * R + by + tx] = (__bf16)t[tx][ty + i];
}

// ---------------- bf16 [S][64] V-slice of qkv -> bf16 Vt[z][64][VSTR] ----------------
__global__ void transpose_v(const __bf16* __restrict__ qkv, __bf16* __restrict__ vtg) {
    __shared__ __bf16 t[32][34];
    const int z = blockIdx.z;           // b*4 + kh
    const int b = z >> 2, kh = z & 3;
    const int s0 = blockIdx.x * 32, d0 = blockIdx.y * 32;
    const int tx = threadIdx.x, ty = threadIdx.y;   // (32, 8)
    const __bf16* src = qkv + (size_t)b * SEQ * QKVN + VOFF + kh * HD;
#pragma unroll
    for (int i = 0; i < 32; i += 8)
        t[ty + i][tx] = src[(size_t)(s0 + ty + i) * QKVN + d0 + tx];
    __syncthreads();
    __bf16* dst = vtg + ((size_t)z * HD + d0) * VSTR + s0;
#pragma unroll
    for (int i = 0; i < 32; i += 8)
        dst[(size_t)(ty + i) * VSTR + tx] = t[tx][ty + i];
}

// ---------------- bf16 GEMM (m97 structure): C[M,N] = A[M,K]*Bt[N,K]^T + bias ----
// QSCALE: multiply cols < 1024 by CSC (pre-scales q for the attention kernel).
template<int OUT_BF16, int QSCALE>
__global__ __launch_bounds__(256) void gemm_bf16(
    const __bf16* __restrict__ A, const __bf16* __restrict__ Bt,
    const float* __restrict__ bias, void* __restrict__ Cout,
    int M, int N, int K)
{
    __shared__ __bf16 Als[128 * 32];   // linear: row*32 + k  (64B rows -> conflict-free b128)
    __shared__ __bf16 Bls[128 * 32];
    const int tid  = threadIdx.x;
    const int lane = tid & 63;
    const int wave = tid >> 6;
    const int lo = lane & 15, hi = lane >> 4;
    const int bm = blockIdx.y * 128, bn = blockIdx.x * 128;
    const int wr = (wave >> 1) * 64, wc = (wave & 1) * 64;

    const __bf16* gA = A  + (size_t)(bm + wave * 32 + (lane >> 2)) * K + (lane & 3) * 8;
    const __bf16* gB = Bt + (size_t)(bn + wave * 32 + (lane >> 2)) * K + (lane & 3) * 8;
    __bf16* lA = &Als[wave * 32 * 32];
    __bf16* lB = &Bls[wave * 32 * 32];

    f32x4 acc[4][4] = {};

    for (int k0 = 0; k0 < K; k0 += 32) {
        __syncthreads();
        GLL16(gA + k0,                  lA);
        GLL16(gA + k0 + (size_t)16 * K, lA + 512);
        GLL16(gB + k0,                  lB);
        GLL16(gB + k0 + (size_t)16 * K, lB + 512);
        __syncthreads();

        bf16x8 af[4], bfr[4];
#pragma unroll
        for (int i = 0; i < 4; i++) {
            af[i]  = *reinterpret_cast<const bf16x8*>(&Als[(wr + i * 16 + lo) * 32 + hi * 8]);
            bfr[i] = *reinterpret_cast<const bf16x8*>(&Bls[(wc + i * 16 + lo) * 32 + hi * 8]);
        }
#pragma unroll
        for (int i = 0; i < 4; i++)
#pragma unroll
            for (int j = 0; j < 4; j++)
                acc[i][j] = __builtin_amdgcn_mfma_f32_16x16x32_bf16(af[i], bfr[j], acc[i][j], 0, 0, 0);
    }

#pragma unroll
    for (int j = 0; j < 4; j++) {
        int col = bn + wc + j * 16 + lo;
        float bv = bias[col];
#pragma unroll
        for (int i = 0; i < 4; i++) {
            int row0 = bm + wr + i * 16 + hi * 4;
#pragma unroll
            for (int rr = 0; rr < 4; rr++) {
                float v = acc[i][j][rr] + bv;
                if (QSCALE && col < DIMD) v *= CSC;
                if (OUT_BF16) ((__bf16*)Cout)[(size_t)(row0 + rr) * N + col] = (__bf16)v;
                else          ((float* )Cout)[(size_t)(row0 + rr) * N + col] = v;
            }
        }
    }
}

// ---------------- causal GQA flash attention ----------------
// 512 blocks x 1024 threads = 16 waves = 4 heads x 2 tiles x 2 key-parities.
// z=bid&7 (XCD pin); p chosen so co-resident blocks (bid, bid+256) carry
// complementary work. Wave owns ONE 16-row tile (T = p or 127-p) and every
// 2nd 64-key chunk (parity). 256-key super-chunks double-buffered in LDS
// (K[128][64]+Vt[64][128] per buf, XOR-pre-swizzled source, 2 GLL/wave/sc).
// Swapped QK^T -> lane holds P[q=lo][k=hi*4+r]: exactly the 16x16x16 mfma
// B-frag, so PV runs P-in-register (no P LDS round-trip); V is the A-operand
// (b64 reads). Fixed-max exp2 softmax; parity partials combined through LDS.
__global__ __launch_bounds__(1024, 8) void attn_fwd(
    const __bf16* __restrict__ qkv, const __bf16* __restrict__ vt, __bf16* __restrict__ y)
{
    __shared__ __bf16 Ka[2][8192];        // [buf][key 128][d 64] swizzled 16B units
    __shared__ __bf16 Va[2][8192];        // [buf][d 64][key 128] swizzled 16B units
    __shared__ float  comb[8 * 64 * 4];   // 8KB parity-combine buffer
#if !HAS_MFMA16
    __shared__ __bf16 Pls[16][16][72];    // fallback P staging (per wave)
#endif
    const int tid  = threadIdx.x;
    const int wave = tid >> 6, lane = tid & 63;
    const int lo = lane & 15, hi = lane >> 4;
    const int head = wave & 3, tt = (wave >> 2) & 1, par = wave >> 3;

    const int bid = blockIdx.x;
    const int z  = bid & 7;                      // b*4 + kh  -> XCD-pinned
    const int b  = z >> 2, kh = z & 3;
    const int c2 = bid >> 3;                     // 0..63
    const int p  = (c2 < 32) ? c2 : 95 - c2;     // co-resident blocks complement
    const int h  = kh * 4 + head;

    const int T  = tt ? 127 - p : p;
    const int qw = T * 16;
    const int cT = (T >> 2) + 1;                 // 64-key chunks for this tile
    const int cMax = ((127 - p) >> 2) + 1;
    const int S = (cMax + 1) >> 1;               // 256-key super-chunks staged

    const __bf16* base = qkv + (size_t)b * SEQ * QKVN;
    const __bf16* qp = base + h * HD;
    const __bf16* kp = base + DIMD + kh * HD;
    const __bf16* vp = vt + (size_t)z * HD * VSTR;   // [64][VSTR]

    // ---- staging sources (XOR-pre-swizzled; LDS dest linear, 1 GLL each) ----
    const int krow = lane >> 3;                         // 0..7
    const __bf16* kst = kp + (size_t)(wave * 8 + krow) * QKVN + ((lane & 7) ^ krow) * 8;
    const int vrow = lane >> 4;                         // 0..3
    const int vsu  = (lane & 15) ^ (4 * (wave & 1) + vrow);
    const __bf16* vst = vp + (size_t)(wave * 4 + vrow) * VSTR + vsu * 8;
    __bf16* kd = &Ka[0][wave * 512];
    __bf16* vd = &Va[0][wave * 512];

#define STAGE(s, buf)                                        \
    do {                                                     \
        GLL16(kst + (size_t)(s) * 128 * QKVN, kd + (buf) * 8192); \
        GLL16(vst + (s) * 128,                vd + (buf) * 8192); \
    } while (0)

    const int xk = lo & 7;
    const int u0 = (hi ^ xk) * 8;          // K d-units hi
    const int u1 = ((hi + 4) ^ xk) * 8;    // K d-units hi+4

    // Q B-frags (pre-scaled by CSC in GEMM1): lane holds Q[qw+lo][hi*8..+8]
    bf16x8 bQ0 = *reinterpret_cast<const bf16x8*>(qp + (size_t)(qw + lo) * QKVN + hi * 8);
    bf16x8 bQ1 = *reinterpret_cast<const bf16x8*>(qp + (size_t)(qw + lo) * QKVN + 32 + hi * 8);

    f32x4 accO[4] = {};
    float ss = 0.0f;

    STAGE(0, 0);
    __syncthreads();

    int cur = 0;
    for (int s = 0; s < S; ++s) {
        if (s + 1 < S) STAGE(s + 1, cur ^ 1);   // in flight across the compute

        const int ce = 2 * s + par;             // this wave's 64-key chunk index
        if (ce < cT) {
            const int kbase = ce * 64;
            const bool dT = (ce == cT - 1);
            const __bf16* Kb = &Ka[cur][(size_t)par * 64 * 64];
            const __bf16* Vb = &Va[cur][0];

#pragma unroll
            for (int ks = 0; ks < 4; ks++) {
                const __bf16* Kr = Kb + (ks * 16 + lo) * 64;
                bf16x8 aK0 = *reinterpret_cast<const bf16x8*>(Kr + u0);
                bf16x8 aK1 = *reinterpret_cast<const bf16x8*>(Kr + u1);
                f32x4 sv = {0.f, 0.f, 0.f, 0.f};
                sv = __builtin_amdgcn_mfma_f32_16x16x32_bf16(aK0, bQ0, sv, 0, 0, 0);
                sv = __builtin_amdgcn_mfma_f32_16x16x32_bf16(aK1, bQ1, sv, 0, 0, 0);

                bf16x4 pk;
#pragma unroll
                for (int r = 0; r < 4; r++) {
                    float e = exp2f(sv[r]);
                    if (dT && (kbase + ks * 16 + hi * 4 + r > qw + lo)) e = 0.0f;
                    ss += e;
                    pk[r] = (__bf16)e;
                }

#if HAS_MFMA16
                // PV: A = Vt frag (b64 from LDS), B = pk in-register.
                // D[d][q]: col=lo=q, row=hi*4+r=d-sub; accO[f] covers d=f*16..+16.
                const int uvb = par * 8 + ks * 2 + (hi >> 1);
                const int voff = (uvb ^ xk) * 8 + (hi & 1) * 4;
#pragma unroll
                for (int f = 0; f < 4; f++) {
                    bf16x4 vf = *reinterpret_cast<const bf16x4*>(&Vb[(f * 16 + lo) * 128] + voff);
                    accO[f] = __builtin_amdgcn_mfma_f32_16x16x16bf16_1k(
                        __builtin_bit_cast(s16x4, vf), __builtin_bit_cast(s16x4, pk),
                        accO[f], 0, 0, 0);
                }
#else
                *reinterpret_cast<bf16x4*>(&Pls[wave][lo][ks * 16 + hi * 4]) = pk;
#endif
            }

#if !HAS_MFMA16
#pragma unroll
            for (int k2 = 0; k2 < 2; k2++) {
                const int uv = ((par * 8 + k2 * 4 + hi) ^ xk) * 8;
                bf16x8 pA = *reinterpret_cast<const bf16x8*>(&Pls[wave][lo][k2 * 32 + hi * 8]);
#pragma unroll
                for (int f = 0; f < 4; f++) {
                    bf16x8 vB = *reinterpret_cast<const bf16x8*>(&Vb[(f * 16 + lo) * 128] + uv);
                    accO[f] = __builtin_amdgcn_mfma_f32_16x16x32_bf16(pA, vB, accO[f], 0, 0, 0);
                }
            }
#endif
        }

        __syncthreads();   // readers done with buf(cur); STAGE(s+1) drained
        cur ^= 1;
    }
#undef STAGE

    // ---- parity combine: 5 rounds of 16B adds through LDS ----
    const int sidx = ((wave & 7) * 64 + lane) * 4;
#pragma unroll
    for (int r = 0; r < 5; r++) {
        if (par == 1) {
            if (r < 4) *reinterpret_cast<f32x4*>(&comb[sidx]) = accO[r];
            else       comb[sidx] = ss;
        }
        __syncthreads();
        if (par == 0) {
            if (r < 4) accO[r] += *reinterpret_cast<const f32x4*>(&comb[sidx]);
            else       ss += comb[sidx];
        }
        __syncthreads();
    }

    if (par == 0) {
#if HAS_MFMA16
        // accO: q = lo (lane-local!), d = f*16 + hi*4 + r
        ss += __shfl_xor(ss, 16);
        ss += __shfl_xor(ss, 32);
        float inv = 1.0f / ss;
        const size_t yb = (size_t)(b * SEQ + qw + lo) * DIMD + h * HD + hi * 4;
#pragma unroll
        for (int f = 0; f < 4; f++) {
            bf16x4 o;
#pragma unroll
            for (int r = 0; r < 4; r++) o[r] = (__bf16)(accO[f][r] * inv);
            *reinterpret_cast<bf16x4*>(&y[yb + f * 16]) = o;
        }
#else
        // accO: q = hi*4+r, d = f*16 + lo
        ss += __shfl_xor(ss, 16);
        ss += __shfl_xor(ss, 32);
#pragma unroll
        for (int r = 0; r < 4; r++) {
            float sr = __shfl(ss, hi * 4 + r);
            float inv = 1.0f / sr;
            int q = qw + hi * 4 + r;
#pragma unroll
            for (int f = 0; f < 4; f++)
                y[(size_t)(b * SEQ + q) * DIMD + h * HD + f * 16 + lo] = (__bf16)(accO[f][r] * inv);
        }
#endif
    }
}

// ---------------- launcher ----------------
extern "C" void kernel_launch(void* const* d_in, const int* in_sizes, int n_in,
                              void* d_out, int out_size, void* d_ws, size_t ws_size,
                              hipStream_t stream) {
    const float* x    = (const float*)d_in[0];
    const float* Wqkv = (const float*)d_in[1];
    const float* bqkv = (const float*)d_in[2];
    const float* Wout = (const float*)d_in[3];
    const float* bout = (const float*)d_in[4];
    float* out = (float*)d_out;

    char* ws = (char*)d_ws;
    __bf16* xb    = (__bf16*)(ws);                          // 8 MB  (x bf16; later reused as y)
    __bf16* wqkvT = (__bf16*)(ws + ((size_t)8  << 20));     // 3 MB  [1536][1024] (dead after GEMM1)
    __bf16* woutT = (__bf16*)(ws + ((size_t)11 << 20));     // 2 MB  [1024][1024]
    __bf16* qkvb  = (__bf16*)(ws + ((size_t)13 << 20));     // 12 MB [4096][1536]
    __bf16* vtg   = wqkvT;                                  // alias: 2.2 MB Vt[8][64][VSTR]
    __bf16* yb    = xb;                                     // alias: xb dead after GEMM1

    const int M = NB * SEQ;   // 4096

    cvt_f32_bf16<<<(M * DIMD / 4 + 255) / 256, 256, 0, stream>>>(x, xb, M * DIMD / 4);
    transpose_cvt<<<dim3(QKVN / 32, DIMD / 32), dim3(32, 8), 0, stream>>>(Wqkv, wqkvT, DIMD, QKVN);
    transpose_cvt<<<dim3(DIMD / 32, DIMD / 32), dim3(32, 8), 0, stream>>>(Wout, woutT, DIMD, DIMD);

    gemm_bf16<1, 1><<<dim3(QKVN / 128, M / 128), 256, 0, stream>>>(xb, wqkvT, bqkv, qkvb, M, QKVN, DIMD);

    transpose_v<<<dim3(SEQ / 32, HD / 32, NB * 4), dim3(32, 8), 0, stream>>>(qkvb, vtg);

    attn_fwd<<<512, 1024, 0, stream>>>(qkvb, vtg, yb);

    gemm_bf16<0, 0><<<dim3(DIMD / 128, M / 128), 256, 0, stream>>>(yb, woutT, bout, out, M, DIMD, DIMD);
}

// Round 12
// 112.888 us; speedup vs baseline: 1.0573x; 1.0573x over previous
//
#include <hip/hip_runtime.h>
#include <cstdint>
#include <cstddef>

// ---------------- types ----------------
typedef __bf16 bf16x8 __attribute__((ext_vector_type(8)));
typedef __bf16 bf16x4 __attribute__((ext_vector_type(4)));
typedef float  f32x4  __attribute__((ext_vector_type(4)));
typedef short  s16x4  __attribute__((ext_vector_type(4)));

#define DIMD 1024
#define SEQ  2048
#define NB   2
#define NH   16
#define HD   64
#define QKVN 1536   // 1024 + 2*256
#define VOFF 1280   // DIMD + 256
#define VSTR 2080   // padded V^T row stride (4160B: breaks L2 channel aliasing)
#define CSC  0.18033688011112042f   // 0.125 * log2(e), folded into q in GEMM1

#if __has_builtin(__builtin_amdgcn_mfma_f32_16x16x16bf16_1k)
#define HAS_MFMA16 1
#else
#define HAS_MFMA16 0
#endif

// async global->LDS (16B per lane, wave-uniform LDS base)
typedef __attribute__((address_space(1))) const void* as1_cvp;
typedef __attribute__((address_space(3))) void* as3_vp;
#define GLL16(g, l) __builtin_amdgcn_global_load_lds((as1_cvp)(const void*)(g), (as3_vp)(void*)(l), 16, 0, 0)

// ---------------- fp32 -> bf16 elementwise (vec4) ----------------
__global__ void cvt_f32_bf16(const float* __restrict__ in, __bf16* __restrict__ out, int n4) {
    int i = blockIdx.x * blockDim.x + threadIdx.x;
    if (i >= n4) return;
    float4 v = reinterpret_cast<const float4*>(in)[i];
    bf16x4 o;
    o[0] = (__bf16)v.x; o[1] = (__bf16)v.y; o[2] = (__bf16)v.z; o[3] = (__bf16)v.w;
    reinterpret_cast<bf16x4*>(out)[i] = o;
}

// ---------------- fp32 [R][C] -> bf16 [C][R] tiled transpose ----------------
__global__ void transpose_cvt(const float* __restrict__ in, __bf16* __restrict__ out, int R, int C) {
    __shared__ float t[32][33];
    int bx = blockIdx.x * 32;
    int by = blockIdx.y * 32;
    int tx = threadIdx.x, ty = threadIdx.y;   // (32, 8)
#pragma unroll
    for (int i = 0; i < 32; i += 8)
        t[ty + i][tx] = in[(size_t)(by + ty + i) * C + bx + tx];
    __syncthreads();
#pragma unroll
    for (int i = 0; i < 32; i += 8)
        out[(size_t)(bx + ty + i) * R + by + tx] = (__bf16)t[tx][ty + i];
}

// ---------------- bf16 [S][64] V-slice of qkv -> bf16 Vt[z][64][VSTR] ----------------
__global__ void transpose_v(const __bf16* __restrict__ qkv, __bf16* __restrict__ vtg) {
    __shared__ __bf16 t[32][34];
    const int z = blockIdx.z;           // b*4 + kh
    const int b = z >> 2, kh = z & 3;
    const int s0 = blockIdx.x * 32, d0 = blockIdx.y * 32;
    const int tx = threadIdx.x, ty = threadIdx.y;   // (32, 8)
    const __bf16* src = qkv + (size_t)b * SEQ * QKVN + VOFF + kh * HD;
#pragma unroll
    for (int i = 0; i < 32; i += 8)
        t[ty + i][tx] = src[(size_t)(s0 + ty + i) * QKVN + d0 + tx];
    __syncthreads();
    __bf16* dst = vtg + ((size_t)z * HD + d0) * VSTR + s0;
#pragma unroll
    for (int i = 0; i < 32; i += 8)
        dst[(size_t)(ty + i) * VSTR + tx] = t[tx][ty + i];
}

// ---------------- bf16 GEMM, 128x64 tile (occupancy-tuned m97 staging) ----------------
// C[M,N] = A[M,K]*Bt[N,K]^T + bias. 1D grid (nx = N/64 fastest), bijective XCD
// swizzle (grid%8==0): each XCD walks contiguous tiles -> A/B panels L2-resident.
// 4 waves (2Mx2N), wave = 64x32 output (4x2 frags). BK=32, linear LDS,
// global_load_lds width-16 (3 instr/wave/k-step).
template<int OUT_BF16, int QSCALE>
__global__ __launch_bounds__(256) void gemm_bf16(
    const __bf16* __restrict__ A, const __bf16* __restrict__ Bt,
    const float* __restrict__ bias, void* __restrict__ Cout,
    int M, int N, int K, int nx)
{
    __shared__ __bf16 Als[128 * 32];   // row*32 + k (64B rows)
    __shared__ __bf16 Bls[64 * 32];
    const int tid  = threadIdx.x;
    const int lane = tid & 63;
    const int wave = tid >> 6;
    const int lo = lane & 15, hi = lane >> 4;

    const int lin = blockIdx.x;
    const int cpx = gridDim.x >> 3;                    // grid % 8 == 0
    const int swz = (lin & 7) * cpx + (lin >> 3);      // XCD-contiguous
    const int bm = (swz / nx) * 128, bn = (swz % nx) * 64;
    const int wr = (wave >> 1) * 64, wc = (wave & 1) * 32;

    const __bf16* gA = A  + (size_t)(bm + wave * 16 + (lane >> 2)) * K + (lane & 3) * 8;
    const __bf16* gB = Bt + (size_t)(bn + wave * 16 + (lane >> 2)) * K + (lane & 3) * 8;
    __bf16* lA = &Als[wave * 16 * 32];
    __bf16* lB = &Bls[wave * 16 * 32];

    f32x4 acc[4][2] = {};

    for (int k0 = 0; k0 < K; k0 += 32) {
        __syncthreads();
        GLL16(gA + k0,                  lA);
        GLL16(gA + k0 + (size_t)64 * K, lA + 2048);
        GLL16(gB + k0,                  lB);
        __syncthreads();

        bf16x8 af[4], bfr[2];
#pragma unroll
        for (int i = 0; i < 4; i++)
            af[i] = *reinterpret_cast<const bf16x8*>(&Als[(wr + i * 16 + lo) * 32 + hi * 8]);
#pragma unroll
        for (int j = 0; j < 2; j++)
            bfr[j] = *reinterpret_cast<const bf16x8*>(&Bls[(wc + j * 16 + lo) * 32 + hi * 8]);
#pragma unroll
        for (int i = 0; i < 4; i++)
#pragma unroll
            for (int j = 0; j < 2; j++)
                acc[i][j] = __builtin_amdgcn_mfma_f32_16x16x32_bf16(af[i], bfr[j], acc[i][j], 0, 0, 0);
    }

#pragma unroll
    for (int j = 0; j < 2; j++) {
        int col = bn + wc + j * 16 + lo;
        float bv = bias[col];
#pragma unroll
        for (int i = 0; i < 4; i++) {
            int row0 = bm + wr + i * 16 + hi * 4;
#pragma unroll
            for (int rr = 0; rr < 4; rr++) {
                float v = acc[i][j][rr] + bv;
                if (QSCALE && col < DIMD) v *= CSC;
                if (OUT_BF16) ((__bf16*)Cout)[(size_t)(row0 + rr) * N + col] = (__bf16)v;
                else          ((float* )Cout)[(size_t)(row0 + rr) * N + col] = v;
            }
        }
    }
}

// ---------------- causal GQA flash attention ----------------
// 512 blocks x 1024 threads = 16 waves = 4 heads x 2 tiles x 2 key-parities.
// z=bid&7 (XCD pin); co-resident blocks carry complementary work. 256-key
// super-chunks double-buffered in LDS (XOR-pre-swizzled source). Swapped QK^T;
// PV via 16x16x16 mfma with P in-register. Fixed-max exp2 softmax; parity
// partials combined through LDS (overlaid on dead K/V buffers, 1 barrier).
__global__ __launch_bounds__(1024, 8) void attn_fwd(
    const __bf16* __restrict__ qkv, const __bf16* __restrict__ vt, __bf16* __restrict__ y)
{
    __shared__ __bf16 Ka[2][8192];        // [buf][key 128][d 64] swizzled 16B units
    __shared__ __bf16 Va[2][8192];        // [buf][d 64][key 128] swizzled 16B units
#if !HAS_MFMA16
    __shared__ __bf16 Pls[16][16][72];    // fallback P staging (per wave)
#endif
    const int tid  = threadIdx.x;
    const int wave = tid >> 6, lane = tid & 63;
    const int lo = lane & 15, hi = lane >> 4;
    const int head = wave & 3, tt = (wave >> 2) & 1, par = wave >> 3;

    const int bid = blockIdx.x;
    const int z  = bid & 7;                      // b*4 + kh  -> XCD-pinned
    const int b  = z >> 2, kh = z & 3;
    const int c2 = bid >> 3;                     // 0..63
    const int p  = (c2 < 32) ? c2 : 95 - c2;     // co-resident blocks complement
    const int h  = kh * 4 + head;

    const int T  = tt ? 127 - p : p;
    const int qw = T * 16;
    const int cT = (T >> 2) + 1;                 // 64-key chunks for this tile
    const int cMax = ((127 - p) >> 2) + 1;
    const int S = (cMax + 1) >> 1;               // 256-key super-chunks staged

    const __bf16* base = qkv + (size_t)b * SEQ * QKVN;
    const __bf16* qp = base + h * HD;
    const __bf16* kp = base + DIMD + kh * HD;
    const __bf16* vp = vt + (size_t)z * HD * VSTR;   // [64][VSTR]

    // ---- staging sources (XOR-pre-swizzled; LDS dest linear, 1 GLL each) ----
    const int krow = lane >> 3;                         // 0..7
    const __bf16* kst = kp + (size_t)(wave * 8 + krow) * QKVN + ((lane & 7) ^ krow) * 8;
    const int vrow = lane >> 4;                         // 0..3
    const int vsu  = (lane & 15) ^ (4 * (wave & 1) + vrow);
    const __bf16* vst = vp + (size_t)(wave * 4 + vrow) * VSTR + vsu * 8;
    __bf16* kd = &Ka[0][wave * 512];
    __bf16* vd = &Va[0][wave * 512];

#define STAGE(s, buf)                                        \
    do {                                                     \
        GLL16(kst + (size_t)(s) * 128 * QKVN, kd + (buf) * 8192); \
        GLL16(vst + (s) * 128,                vd + (buf) * 8192); \
    } while (0)

    const int xk = lo & 7;
    const int u0 = (hi ^ xk) * 8;          // K d-units hi
    const int u1 = ((hi + 4) ^ xk) * 8;    // K d-units hi+4
#if HAS_MFMA16
    int voff[4];
#pragma unroll
    for (int ks = 0; ks < 4; ks++)
        voff[ks] = (((par * 8 + ks * 2 + (hi >> 1)) ^ xk) << 3) + (hi & 1) * 4;
#endif

    // Q B-frags (pre-scaled by CSC in GEMM1): lane holds Q[qw+lo][hi*8..+8]
    bf16x8 bQ0 = *reinterpret_cast<const bf16x8*>(qp + (size_t)(qw + lo) * QKVN + hi * 8);
    bf16x8 bQ1 = *reinterpret_cast<const bf16x8*>(qp + (size_t)(qw + lo) * QKVN + 32 + hi * 8);

    f32x4 accO[4] = {};
    f32x4 ssv = {0.f, 0.f, 0.f, 0.f};

    STAGE(0, 0);
    __syncthreads();

    int cur = 0;
    for (int s = 0; s < S; ++s) {
        if (s + 1 < S) STAGE(s + 1, cur ^ 1);   // in flight across the compute

        const int ce = 2 * s + par;             // this wave's 64-key chunk index
        if (ce < cT) {
            const int kbase = ce * 64;
            const bool dT = (ce == cT - 1);
            const __bf16* Kb = &Ka[cur][(size_t)par * 64 * 64];
            const __bf16* Vb = &Va[cur][0];

#pragma unroll
            for (int ks = 0; ks < 4; ks++) {
                const __bf16* Kr = Kb + (ks * 16 + lo) * 64;
                bf16x8 aK0 = *reinterpret_cast<const bf16x8*>(Kr + u0);
                bf16x8 aK1 = *reinterpret_cast<const bf16x8*>(Kr + u1);
                f32x4 sv = {0.f, 0.f, 0.f, 0.f};
                sv = __builtin_amdgcn_mfma_f32_16x16x32_bf16(aK0, bQ0, sv, 0, 0, 0);
                sv = __builtin_amdgcn_mfma_f32_16x16x32_bf16(aK1, bQ1, sv, 0, 0, 0);

                bf16x4 pk;
#pragma unroll
                for (int r = 0; r < 4; r++) {
                    float e = exp2f(sv[r]);
                    if (dT && (kbase + ks * 16 + hi * 4 + r > qw + lo)) e = 0.0f;
                    ssv[r] += e;
                    pk[r] = (__bf16)e;
                }

#if HAS_MFMA16
                // PV: A = Vt frag (b64 from LDS), B = pk in-register.
#pragma unroll
                for (int f = 0; f < 4; f++) {
                    bf16x4 vf = *reinterpret_cast<const bf16x4*>(&Vb[(f * 16 + lo) * 128] + voff[ks]);
                    accO[f] = __builtin_amdgcn_mfma_f32_16x16x16bf16_1k(
                        __builtin_bit_cast(s16x4, vf), __builtin_bit_cast(s16x4, pk),
                        accO[f], 0, 0, 0);
                }
#else
                *reinterpret_cast<bf16x4*>(&Pls[wave][lo][ks * 16 + hi * 4]) = pk;
#endif
            }

#if !HAS_MFMA16
#pragma unroll
            for (int k2 = 0; k2 < 2; k2++) {
                const int uv = ((par * 8 + k2 * 4 + hi) ^ xk) * 8;
                bf16x8 pA = *reinterpret_cast<const bf16x8*>(&Pls[wave][lo][k2 * 32 + hi * 8]);
#pragma unroll
                for (int f = 0; f < 4; f++) {
                    bf16x8 vB = *reinterpret_cast<const bf16x8*>(&Vb[(f * 16 + lo) * 128] + uv);
                    accO[f] = __builtin_amdgcn_mfma_f32_16x16x32_bf16(pA, vB, accO[f], 0, 0, 0);
                }
            }
#endif
        }

        __syncthreads();   // readers done with buf(cur); STAGE(s+1) drained
        cur ^= 1;
    }
#undef STAGE

    float ss = (ssv[0] + ssv[1]) + (ssv[2] + ssv[3]);

    // ---- parity combine: single barrier, buffer overlaid on dead K/V LDS ----
    float* comb = (float*)&Ka[0][0];             // 8 waves x 64 lanes x 80B = 40KB
    const int sidx = ((wave & 7) * 64 + lane) * 20;
    if (par == 1) {
#pragma unroll
        for (int f = 0; f < 4; f++)
            *reinterpret_cast<f32x4*>(&comb[sidx + f * 4]) = accO[f];
        comb[sidx + 16] = ss;
    }
    __syncthreads();
    if (par == 0) {
#pragma unroll
        for (int f = 0; f < 4; f++)
            accO[f] += *reinterpret_cast<const f32x4*>(&comb[sidx + f * 4]);
        ss += comb[sidx + 16];

#if HAS_MFMA16
        // accO: q = lo (lane-local), d = f*16 + hi*4 + r
        ss += __shfl_xor(ss, 16);
        ss += __shfl_xor(ss, 32);
        float inv = 1.0f / ss;
        const size_t yb = (size_t)(b * SEQ + qw + lo) * DIMD + h * HD + hi * 4;
#pragma unroll
        for (int f = 0; f < 4; f++) {
            bf16x4 o;
#pragma unroll
            for (int r = 0; r < 4; r++) o[r] = (__bf16)(accO[f][r] * inv);
            *reinterpret_cast<bf16x4*>(&y[yb + f * 16]) = o;
        }
#else
        // accO: q = hi*4+r, d = f*16 + lo
        ss += __shfl_xor(ss, 16);
        ss += __shfl_xor(ss, 32);
#pragma unroll
        for (int r = 0; r < 4; r++) {
            float sr = __shfl(ss, hi * 4 + r);
            float inv = 1.0f / sr;
            int q = qw + hi * 4 + r;
#pragma unroll
            for (int f = 0; f < 4; f++)
                y[(size_t)(b * SEQ + q) * DIMD + h * HD + f * 16 + lo] = (__bf16)(accO[f][r] * inv);
        }
#endif
    }
}

// ---------------- launcher ----------------
extern "C" void kernel_launch(void* const* d_in, const int* in_sizes, int n_in,
                              void* d_out, int out_size, void* d_ws, size_t ws_size,
                              hipStream_t stream) {
    const float* x    = (const float*)d_in[0];
    const float* Wqkv = (const float*)d_in[1];
    const float* bqkv = (const float*)d_in[2];
    const float* Wout = (const float*)d_in[3];
    const float* bout = (const float*)d_in[4];
    float* out = (float*)d_out;

    char* ws = (char*)d_ws;
    __bf16* xb    = (__bf16*)(ws);                          // 8 MB  (x bf16; later reused as y)
    __bf16* wqkvT = (__bf16*)(ws + ((size_t)8  << 20));     // 3 MB  [1536][1024] (dead after GEMM1)
    __bf16* woutT = (__bf16*)(ws + ((size_t)11 << 20));     // 2 MB  [1024][1024]
    __bf16* qkvb  = (__bf16*)(ws + ((size_t)13 << 20));     // 12 MB [4096][1536]
    __bf16* vtg   = wqkvT;                                  // alias: 2.2 MB Vt[8][64][VSTR]
    __bf16* yb    = xb;                                     // alias: xb dead after GEMM1

    const int M = NB * SEQ;   // 4096

    cvt_f32_bf16<<<(M * DIMD / 4 + 255) / 256, 256, 0, stream>>>(x, xb, M * DIMD / 4);
    transpose_cvt<<<dim3(QKVN / 32, DIMD / 32), dim3(32, 8), 0, stream>>>(Wqkv, wqkvT, DIMD, QKVN);
    transpose_cvt<<<dim3(DIMD / 32, DIMD / 32), dim3(32, 8), 0, stream>>>(Wout, woutT, DIMD, DIMD);

    // 128x64 tiles: 768 blocks (3/CU), XCD-swizzled
    gemm_bf16<1, 1><<<(M / 128) * (QKVN / 64), 256, 0, stream>>>(
        xb, wqkvT, bqkv, qkvb, M, QKVN, DIMD, QKVN / 64);

    transpose_v<<<dim3(SEQ / 32, HD / 32, NB * 4), dim3(32, 8), 0, stream>>>(qkvb, vtg);

    attn_fwd<<<512, 1024, 0, stream>>>(qkvb, vtg, yb);

    // 128x64 tiles: 512 blocks (2/CU), XCD-swizzled
    gemm_bf16<0, 0><<<(M / 128) * (DIMD / 64), 256, 0, stream>>>(
        yb, woutT, bout, out, M, DIMD, DIMD, DIMD / 64);
}